// Round 2
// baseline (1544.536 us; speedup 1.0000x reference)
//
#include <hip/hip_runtime.h>
#include <hip/hip_bf16.h>
#include <math.h>

#define NS 255
#define NB 64
#define NE 200
#define NH 300
#define NH3 900

// ws layout: ws[0..15] = header (int mode at ws[0]); then H [255*64*300] f32; then C.
#define HC_ELEMS (NS * NB * NH)

__device__ __forceinline__ float sigmoidf_(float x) {
    return 1.0f / (1.0f + __expf(-x));
}

// MODE 0 = inputs are fp32; MODE 1 = inputs are bf16
template<int MODE>
__device__ __forceinline__ float LD(const void* p, long i) {
    if (MODE) return __bfloat162float(((const __hip_bfloat16*)p)[i]);
    return ((const float*)p)[i];
}

// Dtype probe: scan first n_units 2-byte units of a float-weight buffer.
// Genuine bf16 weights (|v| < 1) never have exponent >= 0xC0 (|v| >= 2^65 / NaN / Inf).
// fp32 data read as 2-byte units has uniform-random low halves -> such patterns certain.
__global__ __launch_bounds__(256) void detect_kernel(const unsigned short* __restrict__ w,
                                                     int n_units, int* __restrict__ mode)
{
    __shared__ int bad_s;
    if (threadIdx.x == 0) bad_s = 0;
    __syncthreads();
    int bad = 0;
    for (int i = threadIdx.x; i < n_units; i += blockDim.x) {
        unsigned short u = w[i];
        int e = (u >> 7) & 0xFF;
        if (e >= 0xC0) bad++;
    }
    if (bad) atomicAdd(&bad_s, bad);
    __syncthreads();
    if (threadIdx.x == 0) *mode = (bad_s > 0) ? 0 : 1;   // bad patterns => fp32 storage
}

// Level 7: leaves (nodes 127..254). c = sig(i)*tanh(u); h = sig(o)*tanh(c)
template<int MODE>
__global__ __launch_bounds__(256) void leaf_kernel(
    const int* __restrict__ mode,
    const int* __restrict__ x, const void* __restrict__ embed,
    const void* __restrict__ W_iou, const void* __restrict__ b_iou,
    float* __restrict__ H, float* __restrict__ C)
{
    if (*mode != MODE) return;
    int t = blockIdx.x * blockDim.x + threadIdx.x;
    const int total = 128 * NB * NH;
    if (t >= total) return;
    int j   = t % NH;
    int row = t / NH;           // (p-127)*NB + b
    int b   = row % NB;
    int p   = 127 + row / NB;

    int tok = x[p * NB + b];

    float ai = 0.f, ao = 0.f, au = 0.f;
    #pragma unroll 4
    for (int k = 0; k < NE; ++k) {
        float ek = LD<MODE>(embed, (long)tok * NE + k);
        long w = (long)k * NH3;
        ai += ek * LD<MODE>(W_iou, w + j);
        ao += ek * LD<MODE>(W_iou, w + NH + j);
        au += ek * LD<MODE>(W_iou, w + 2 * NH + j);
    }
    ai += LD<MODE>(b_iou, j);
    ao += LD<MODE>(b_iou, NH + j);
    au += LD<MODE>(b_iou, 2 * NH + j);

    float c = sigmoidf_(ai) * tanhf(au);
    float h = sigmoidf_(ao) * tanhf(c);
    int idx = (p * NB + b) * NH + j;
    C[idx] = c;
    H[idx] = h;
}

// Levels 6..0: internal nodes. Children 2p+1, 2p+2 already computed.
template<int MODE>
__global__ __launch_bounds__(256) void internal_kernel(
    const int* __restrict__ mode,
    const int* __restrict__ x, const void* __restrict__ embed,
    const void* __restrict__ W_iou, const void* __restrict__ U_iou,
    const void* __restrict__ b_iou,
    const void* __restrict__ W_f, const void* __restrict__ U_f,
    const void* __restrict__ b_f,
    float* __restrict__ H, float* __restrict__ C,
    int base, int count)
{
    if (*mode != MODE) return;
    int t = blockIdx.x * blockDim.x + threadIdx.x;
    int total = count * NB * NH;
    if (t >= total) return;
    int j   = t % NH;
    int row = t / NH;
    int b   = row % NB;
    int p   = base + row / NB;
    int l = 2 * p + 1, r = 2 * p + 2;

    const float* Hl = H + (l * NB + b) * NH;
    const float* Hr = H + (r * NB + b) * NH;

    int tok = x[p * NB + b];

    // Embedding contributions: W_iou cols (j, 300+j, 600+j) and W_f col j
    float ai = 0.f, ao = 0.f, au = 0.f, af = 0.f;
    #pragma unroll 4
    for (int k = 0; k < NE; ++k) {
        float ek = LD<MODE>(embed, (long)tok * NE + k);
        long w = (long)k * NH3;
        ai += ek * LD<MODE>(W_iou, w + j);
        ao += ek * LD<MODE>(W_iou, w + NH + j);
        au += ek * LD<MODE>(W_iou, w + 2 * NH + j);
        af += ek * LD<MODE>(W_f, (long)k * NH + j);
    }
    // Recurrent contributions: h_sum @ U_iou, H_l @ U_f, H_r @ U_f
    float afl = 0.f, afr = 0.f;
    #pragma unroll 4
    for (int k = 0; k < NH; ++k) {
        float hl = Hl[k], hr = Hr[k];
        float hs = hl + hr;
        long u = (long)k * NH3;
        ai  += hs * LD<MODE>(U_iou, u + j);
        ao  += hs * LD<MODE>(U_iou, u + NH + j);
        au  += hs * LD<MODE>(U_iou, u + 2 * NH + j);
        float uf = LD<MODE>(U_f, (long)k * NH + j);
        afl += hl * uf;
        afr += hr * uf;
    }
    ai += LD<MODE>(b_iou, j);
    ao += LD<MODE>(b_iou, NH + j);
    au += LD<MODE>(b_iou, 2 * NH + j);
    float wf = af + LD<MODE>(b_f, j);

    float fl = sigmoidf_(wf + afl);
    float fr = sigmoidf_(wf + afr);
    float cl = C[(l * NB + b) * NH + j];
    float cr = C[(r * NB + b) * NH + j];

    float c = sigmoidf_(ai) * tanhf(au) + fl * cl + fr * cr;
    float h = sigmoidf_(ao) * tanhf(c);
    int idx = (p * NB + b) * NH + j;
    C[idx] = c;
    H[idx] = h;
}

// Root hidden -> logits -> log_softmax (B=64 rows, 2 classes)
template<int MODE>
__global__ __launch_bounds__(64) void out_kernel(
    const int* __restrict__ mode,
    const float* __restrict__ H,
    const void* __restrict__ W_out, const void* __restrict__ b_out,
    void* __restrict__ out)
{
    if (*mode != MODE) return;
    int b = threadIdx.x;
    if (b >= NB) return;
    const float* h = H + b * NH;   // node 0 rows
    float l0 = 0.f, l1 = 0.f;
    #pragma unroll 4
    for (int k = 0; k < NH; ++k) {
        float hk = h[k];
        l0 += hk * LD<MODE>(W_out, k * 2);
        l1 += hk * LD<MODE>(W_out, k * 2 + 1);
    }
    l0 += LD<MODE>(b_out, 0);
    l1 += LD<MODE>(b_out, 1);
    float m = fmaxf(l0, l1);
    float lse = m + logf(__expf(l0 - m) + __expf(l1 - m));
    if (MODE) {
        __hip_bfloat16* o = (__hip_bfloat16*)out;
        o[b * 2 + 0] = __float2bfloat16(l0 - lse);
        o[b * 2 + 1] = __float2bfloat16(l1 - lse);
    } else {
        float* o = (float*)out;
        o[b * 2 + 0] = l0 - lse;
        o[b * 2 + 1] = l1 - lse;
    }
}

extern "C" void kernel_launch(void* const* d_in, const int* in_sizes, int n_in,
                              void* d_out, int out_size, void* d_ws, size_t ws_size,
                              hipStream_t stream)
{
    const int*  x      = (const int*)d_in[0];
    // d_in[1] = parent, d_in[2] = depth: complete binary tree, computed arithmetically
    const void* embed  = d_in[3];
    const void* W_iou  = d_in[4];
    const void* U_iou  = d_in[5];
    const void* b_iou  = d_in[6];
    const void* W_f    = d_in[7];
    const void* U_f    = d_in[8];
    const void* b_f    = d_in[9];
    const void* W_out  = d_in[10];
    const void* b_out  = d_in[11];

    int*   mode = (int*)d_ws;
    float* H    = (float*)d_ws + 16;
    float* C    = H + HC_ELEMS;

    // Probe storage dtype of the float weights (W_iou, 180000 elements).
    // Reading 180000 ushorts = 360KB is within the buffer under both layouts.
    detect_kernel<<<1, 256, 0, stream>>>((const unsigned short*)W_iou,
                                         in_sizes[4], mode);

    // Level 7: leaves
    {
        int total = 128 * NB * NH;
        int grid = (total + 255) / 256;
        leaf_kernel<0><<<grid, 256, 0, stream>>>(mode, x, embed, W_iou, b_iou, H, C);
        leaf_kernel<1><<<grid, 256, 0, stream>>>(mode, x, embed, W_iou, b_iou, H, C);
    }
    // Levels 6..0
    for (int d = 6; d >= 0; --d) {
        int base  = (1 << d) - 1;
        int count = 1 << d;
        int total = count * NB * NH;
        int grid = (total + 255) / 256;
        internal_kernel<0><<<grid, 256, 0, stream>>>(mode, x, embed, W_iou, U_iou, b_iou,
                                                     W_f, U_f, b_f, H, C, base, count);
        internal_kernel<1><<<grid, 256, 0, stream>>>(mode, x, embed, W_iou, U_iou, b_iou,
                                                     W_f, U_f, b_f, H, C, base, count);
    }
    out_kernel<0><<<1, 64, 0, stream>>>(mode, H, W_out, b_out, d_out);
    out_kernel<1><<<1, 64, 0, stream>>>(mode, H, W_out, b_out, d_out);
}

// Round 3
// 406.924 us; speedup vs baseline: 3.7956x; 3.7956x over previous
//
#include <hip/hip_runtime.h>
#include <hip/hip_bf16.h>
#include <math.h>

#define NS 255
#define NB 64
#define NE 200
#define NH 300
#define KPH 320   // padded K for H-side GEMMs (300 -> 320)
#define KPE 224   // padded K for emb-side GEMMs (200 -> 224)
#define NPAD 320  // padded N per gate (300 -> 320)

// ws layout (bytes, all 16B aligned):
//  Hbf  [255*64][320] bf16          @ 0          (10,444,800)
//  C    [255*64][300] f32           @ 10,444,800 (19,584,000)
//  Aemb [255*64][224] bf16          @ 30,028,800 ( 7,311,360)
//  UiT  [3][320n][320k] bf16        @ 37,340,160 (   614,400)
//  UfT  [320n][320k] bf16           @ 37,954,560 (   204,800)
//  WgT  [3][320n][224k] bf16        @ 38,159,360 (   430,080)
//  WfT  [320n][224k] bf16           @ 38,589,440 (   143,360)
//  end  38,732,800  (< 39,168,064 proven available)

typedef __attribute__((ext_vector_type(8))) short short8;
typedef __attribute__((ext_vector_type(4))) float f32x4;

__device__ __forceinline__ float sigmoidf_(float x) {
    return 1.0f / (1.0f + __expf(-x));
}
__device__ __forceinline__ unsigned short f2bf(float v) {
    union { __hip_bfloat16 b; unsigned short u; } cv;
    cv.b = __float2bfloat16(v);
    return cv.u;
}
__device__ __forceinline__ float bf2f(unsigned short u) {
    union { unsigned short u; __hip_bfloat16 b; } cv;
    cv.u = u;
    return __bfloat162float(cv.b);
}

// ---------------- prep: weights transpose+pad+bf16, emb gather, H pad zero ---
__global__ __launch_bounds__(256) void prep_kernel(
    const float* __restrict__ U_iou, const float* __restrict__ U_f,
    const float* __restrict__ W_iou, const float* __restrict__ W_f,
    const float* __restrict__ embed, const int* __restrict__ x,
    unsigned short* __restrict__ UiT, unsigned short* __restrict__ UfT,
    unsigned short* __restrict__ WgT, unsigned short* __restrict__ WfT,
    unsigned short* __restrict__ Aemb, unsigned short* __restrict__ Hbf)
{
    const int nUi = 3 * NPAD * KPH;     // 307200
    const int nUf = NPAD * KPH;         // 102400
    const int nWg = 3 * NPAD * KPE;     // 215040
    const int nWf = NPAD * KPE;         // 71680
    const int nAe = NS * NB * KPE;      // 3655680
    const int nHp = NS * NB * (KPH - NH); // 326400
    const int total = nUi + nUf + nWg + nWf + nAe + nHp;
    int stride = gridDim.x * blockDim.x;
    for (int i = blockIdx.x * blockDim.x + threadIdx.x; i < total; i += stride) {
        int idx = i;
        if (idx < nUi) {
            int k = idx % KPH, n = (idx / KPH) % NPAD, g = idx / (KPH * NPAD);
            float v = (n < NH && k < NH) ? U_iou[k * 900 + g * NH + n] : 0.f;
            UiT[idx] = f2bf(v);
        } else if ((idx -= nUi) < nUf) {
            int k = idx % KPH, n = idx / KPH;
            float v = (n < NH && k < NH) ? U_f[k * NH + n] : 0.f;
            UfT[idx] = f2bf(v);
        } else if ((idx -= nUf) < nWg) {
            int k = idx % KPE, n = (idx / KPE) % NPAD, g = idx / (KPE * NPAD);
            float v = (n < NH && k < NE) ? W_iou[k * 900 + g * NH + n] : 0.f;
            WgT[idx] = f2bf(v);
        } else if ((idx -= nWg) < nWf) {
            int k = idx % KPE, n = idx / KPE;
            float v = (n < NH && k < NE) ? W_f[k * NH + n] : 0.f;
            WfT[idx] = f2bf(v);
        } else if ((idx -= nWf) < nAe) {
            int k = idx % KPE, row = idx / KPE;
            float v = 0.f;
            if (k < NE) {
                int tok = x[row];
                v = embed[(size_t)tok * NE + k];
            }
            Aemb[idx] = f2bf(v);
        } else {
            idx -= nAe;
            int kp = idx % (KPH - NH), row = idx / (KPH - NH);
            Hbf[row * KPH + NH + kp] = 0;
        }
    }
}

// ---------------- MFMA strip GEMM: 64M x 64N, A[64][ldA], BT[n][ldB] --------
__device__ __forceinline__ void gemm64(
    f32x4 acc[4][4], const unsigned short* __restrict__ A, int ldA,
    const unsigned short* __restrict__ B, int ldB, int nk, int ln, int quad)
{
    const unsigned short* Ab = A + ln * ldA + quad * 8;
    const unsigned short* Bb = B + ln * ldB + quad * 8;
    for (int kk = 0; kk < nk; ++kk) {
        int ko = kk * 32;
        short8 a0 = *(const short8*)(Ab + ko);
        short8 a1 = *(const short8*)(Ab + 16 * ldA + ko);
        short8 a2 = *(const short8*)(Ab + 32 * ldA + ko);
        short8 a3 = *(const short8*)(Ab + 48 * ldA + ko);
#pragma unroll
        for (int t = 0; t < 4; ++t) {
            short8 b = *(const short8*)(Bb + t * 16 * ldB + ko);
            acc[t][0] = __builtin_amdgcn_mfma_f32_16x16x32_bf16(a0, b, acc[t][0], 0, 0, 0);
            acc[t][1] = __builtin_amdgcn_mfma_f32_16x16x32_bf16(a1, b, acc[t][1], 0, 0, 0);
            acc[t][2] = __builtin_amdgcn_mfma_f32_16x16x32_bf16(a2, b, acc[t][2], 0, 0, 0);
            acc[t][3] = __builtin_amdgcn_mfma_f32_16x16x32_bf16(a3, b, acc[t][3], 0, 0, 0);
        }
    }
}

// ---------------- fused per-level kernel ------------------------------------
// grid: (5, count). block 320 = 5 waves.
// wave 0..2: gate i/o/u preact = emb@Wg + Hl@Ui[g] + Hr@Ui[g]
// wave 3:    fl preact = emb@Wf + Hl@Uf
// wave 4:    fr preact = emb@Wf + Hr@Uf
__global__ __launch_bounds__(320) void level_kernel(
    const unsigned short* __restrict__ Aemb,
    const unsigned short* __restrict__ UiT, const unsigned short* __restrict__ UfT,
    const unsigned short* __restrict__ WgT, const unsigned short* __restrict__ WfT,
    const float* __restrict__ b_iou, const float* __restrict__ b_f,
    unsigned short* __restrict__ Hbf, float* __restrict__ C,
    int base, int is_leaf)
{
    int p = base + blockIdx.y;
    int j0 = blockIdx.x * 64;
    int tid = threadIdx.x;
    int w = tid >> 6, lane = tid & 63, ln = lane & 15, quad = lane >> 4;
    int l = 2 * p + 1, r = 2 * p + 2;

    f32x4 acc[4][4];
#pragma unroll
    for (int t = 0; t < 4; ++t)
#pragma unroll
        for (int s = 0; s < 4; ++s) acc[t][s] = (f32x4){0.f, 0.f, 0.f, 0.f};

    const unsigned short* Ae = Aemb + (size_t)p * NB * KPE;
    if (w < 3) {
        const unsigned short* Bg = WgT + ((size_t)w * NPAD + j0) * KPE;
        gemm64(acc, Ae, KPE, Bg, KPE, 7, ln, quad);
        if (!is_leaf) {
            const unsigned short* Bu = UiT + ((size_t)w * NPAD + j0) * KPH;
            gemm64(acc, Hbf + (size_t)l * NB * KPH, KPH, Bu, KPH, 10, ln, quad);
            gemm64(acc, Hbf + (size_t)r * NB * KPH, KPH, Bu, KPH, 10, ln, quad);
        }
    } else if (!is_leaf) {
        gemm64(acc, Ae, KPE, WfT + (size_t)j0 * KPE, KPE, 7, ln, quad);
        int ch = (w == 3) ? l : r;
        gemm64(acc, Hbf + (size_t)ch * NB * KPH, KPH, UfT + (size_t)j0 * KPH, KPH, 10, ln, quad);
    }

    __shared__ float tile[5][64][16];   // 20 KB
    for (int t = 0; t < 4; ++t) {
        if (t) __syncthreads();
#pragma unroll
        for (int ms = 0; ms < 4; ++ms)
#pragma unroll
            for (int rr = 0; rr < 4; ++rr)
                tile[w][ms * 16 + quad * 4 + rr][ln] = acc[t][ms][rr];
        __syncthreads();
        int jt = j0 + t * 16;
        for (int idx = tid; idx < 1024; idx += 320) {
            int m = idx >> 4, n = idx & 15;
            int j = jt + n;
            if (j < NH) {
                float pi = tile[0][m][n] + b_iou[j];
                float po = tile[1][m][n] + b_iou[NH + j];
                float pu = tile[2][m][n] + b_iou[2 * NH + j];
                float cc;
                if (is_leaf) {
                    cc = sigmoidf_(pi) * tanhf(pu);
                } else {
                    float bj = b_f[j];
                    float fl = sigmoidf_(tile[3][m][n] + bj);
                    float fr = sigmoidf_(tile[4][m][n] + bj);
                    cc = sigmoidf_(pi) * tanhf(pu)
                       + fl * C[((size_t)l * NB + m) * NH + j]
                       + fr * C[((size_t)r * NB + m) * NH + j];
                }
                float hh = sigmoidf_(po) * tanhf(cc);
                C[((size_t)p * NB + m) * NH + j] = cc;
                Hbf[((size_t)p * NB + m) * KPH + j] = f2bf(hh);
            }
        }
    }
}

// ---------------- root -> logits -> log_softmax -----------------------------
__global__ __launch_bounds__(64) void out_kernel(
    const unsigned short* __restrict__ Hbf,
    const float* __restrict__ W_out, const float* __restrict__ b_out,
    float* __restrict__ out)
{
    int b = threadIdx.x;
    const unsigned short* h = Hbf + (size_t)b * KPH;  // node 0 rows
    float l0 = 0.f, l1 = 0.f;
#pragma unroll 4
    for (int k = 0; k < NH; ++k) {
        float hk = bf2f(h[k]);
        l0 += hk * W_out[k * 2];
        l1 += hk * W_out[k * 2 + 1];
    }
    l0 += b_out[0];
    l1 += b_out[1];
    float m = fmaxf(l0, l1);
    float lse = m + logf(__expf(l0 - m) + __expf(l1 - m));
    out[b * 2 + 0] = l0 - lse;
    out[b * 2 + 1] = l1 - lse;
}

extern "C" void kernel_launch(void* const* d_in, const int* in_sizes, int n_in,
                              void* d_out, int out_size, void* d_ws, size_t ws_size,
                              hipStream_t stream)
{
    const int*   x     = (const int*)d_in[0];
    const float* embed = (const float*)d_in[3];
    const float* W_iou = (const float*)d_in[4];
    const float* U_iou = (const float*)d_in[5];
    const float* b_iou = (const float*)d_in[6];
    const float* W_f   = (const float*)d_in[7];
    const float* U_f   = (const float*)d_in[8];
    const float* b_f   = (const float*)d_in[9];
    const float* W_out = (const float*)d_in[10];
    const float* b_out = (const float*)d_in[11];

    char* ws = (char*)d_ws;
    unsigned short* Hbf  = (unsigned short*)(ws + 0);
    float*          C    = (float*)(ws + 10444800);
    unsigned short* Aemb = (unsigned short*)(ws + 30028800);
    unsigned short* UiT  = (unsigned short*)(ws + 37340160);
    unsigned short* UfT  = (unsigned short*)(ws + 37954560);
    unsigned short* WgT  = (unsigned short*)(ws + 38159360);
    unsigned short* WfT  = (unsigned short*)(ws + 38589440);

    prep_kernel<<<2048, 256, 0, stream>>>(U_iou, U_f, W_iou, W_f, embed, x,
                                          UiT, UfT, WgT, WfT, Aemb, Hbf);

    for (int d = 7; d >= 0; --d) {
        int base = (1 << d) - 1;
        int count = 1 << d;
        dim3 grid(5, count);
        level_kernel<<<grid, 320, 0, stream>>>(Aemb, UiT, UfT, WgT, WfT,
                                               b_iou, b_f, Hbf, C, base, d == 7 ? 1 : 0);
    }
    out_kernel<<<1, 64, 0, stream>>>(Hbf, W_out, b_out, (float*)d_out);
}

// Round 4
// 362.617 us; speedup vs baseline: 4.2594x; 1.1222x over previous
//
#include <hip/hip_runtime.h>
#include <hip/hip_bf16.h>
#include <math.h>

#define NS 255
#define NB 64
#define NE 200
#define NH 300
#define TS 2048          // shorts per 4KB tile (64 rows x 32 k)

// ws layout (bytes):
//  HbfT  [255][10][TS] bf16 tiled/swizzled  @ 0           (10,444,800)
//  C     [255*64][300] f32                  @ 10,444,800  (19,584,000)
//  AembT [255][7][TS] bf16 tiled/swizzled   @ 30,028,800  ( 7,311,360)
//  BW    [4][5][17][TS] bf16 tiled/swizzled @ 37,340,160  ( 1,392,640)
//  end 38,732,800 (fits: 38,732,800 proven in R3)

typedef __attribute__((ext_vector_type(8))) short short8;
typedef __attribute__((ext_vector_type(4))) float f32x4;

__device__ __forceinline__ float sigmoidf_(float x) { return 1.0f / (1.0f + __expf(-x)); }
__device__ __forceinline__ unsigned short f2bf(float v) {
    union { __hip_bfloat16 b; unsigned short u; } cv; cv.b = __float2bfloat16(v); return cv.u;
}
__device__ __forceinline__ float bf2f(unsigned short u) {
    union { unsigned short u; __hip_bfloat16 b; } cv; cv.u = u; return __bfloat162float(cv.b);
}
// swizzled element offset (shorts) within a 64x32 tile
__device__ __forceinline__ int swz(int row, int kk) {
    int g = (kk >> 3) ^ ((row >> 1) & 3);
    return ((row << 2) + g) * 8 + (kk & 7);
}

// ---------------- prep: pre-tile weights + embeddings into swizzled tiles ---
__global__ __launch_bounds__(256) void prep_kernel(
    const float* __restrict__ U_iou, const float* __restrict__ U_f,
    const float* __restrict__ W_iou, const float* __restrict__ W_f,
    const float* __restrict__ embed, const int* __restrict__ x,
    unsigned short* __restrict__ BW, unsigned short* __restrict__ AembT)
{
    const int nBW = 4 * 5 * 17 * TS;   // 696320
    const int nAe = NS * 7 * TS;       // 3655680
    int total = nBW + nAe;
    int stride = gridDim.x * blockDim.x;
    for (int i = blockIdx.x * blockDim.x + threadIdx.x; i < total; i += stride) {
        if (i < nBW) {
            int e = i & (TS - 1), tile = i >> 11;
            int c = tile % 17, t2 = tile / 17;
            int s = t2 % 5, g = t2 / 5;
            int row = e >> 5, pos = (e >> 3) & 3;
            int kk = ((pos ^ ((row >> 1) & 3)) << 3) + (e & 7);
            int j = s * 64 + row;
            float v = 0.f;
            if (c < 7) {
                int k = c * 32 + kk;
                if (j < NH && k < NE) v = (g < 3) ? W_iou[k * 900 + g * NH + j] : W_f[k * NH + j];
            } else {
                int k = (c - 7) * 32 + kk;
                if (j < NH && k < NH) v = (g < 3) ? U_iou[k * 900 + g * NH + j] : U_f[k * NH + j];
            }
            BW[i] = f2bf(v);
        } else {
            int i2 = i - nBW;
            int e = i2 & (TS - 1), tile = i2 >> 11;
            int c = tile % 7, node = tile / 7;
            int row = e >> 5, pos = (e >> 3) & 3;    // row = batch b
            int kk = ((pos ^ ((row >> 1) & 3)) << 3) + (e & 7);
            int k = c * 32 + kk;
            float v = 0.f;
            if (k < NE) v = embed[(size_t)x[node * NB + row] * NE + k];
            AembT[i2] = f2bf(v);
        }
    }
}

// stage one 4KB tile: 4 issues of 64 lanes x 16B, lane-contiguous
__device__ __forceinline__ void stage_tile(const unsigned short* __restrict__ g,
                                           unsigned short* l, int lane)
{
#pragma unroll
    for (int i = 0; i < 4; ++i)
        __builtin_amdgcn_global_load_lds(
            (const __attribute__((address_space(1))) unsigned short*)(g + i * 512 + lane * 8),
            (__attribute__((address_space(3))) unsigned short*)(l + i * 512 + lane * 8),
            16, 0, 0);
}

// one K=32 chunk: A tile x B tile -> acc (64x64), fragments from swizzled LDS
__device__ __forceinline__ void mfma_chunk(f32x4 acc[4][4],
                                           const unsigned short* At,
                                           const unsigned short* Bt,
                                           int ln, int quad)
{
    short8 a0 = *(const short8*)(At + ((ln)      * 4 + (quad ^ (((ln)      >> 1) & 3))) * 8);
    short8 a1 = *(const short8*)(At + ((ln + 16) * 4 + (quad ^ (((ln + 16) >> 1) & 3))) * 8);
    short8 a2 = *(const short8*)(At + ((ln + 32) * 4 + (quad ^ (((ln + 32) >> 1) & 3))) * 8);
    short8 a3 = *(const short8*)(At + ((ln + 48) * 4 + (quad ^ (((ln + 48) >> 1) & 3))) * 8);
#pragma unroll
    for (int t = 0; t < 4; ++t) {
        int bc = ln + t * 16;
        short8 b = *(const short8*)(Bt + (bc * 4 + (quad ^ ((bc >> 1) & 3))) * 8);
        acc[t][0] = __builtin_amdgcn_mfma_f32_16x16x32_bf16(a0, b, acc[t][0], 0, 0, 0);
        acc[t][1] = __builtin_amdgcn_mfma_f32_16x16x32_bf16(a1, b, acc[t][1], 0, 0, 0);
        acc[t][2] = __builtin_amdgcn_mfma_f32_16x16x32_bf16(a2, b, acc[t][2], 0, 0, 0);
        acc[t][3] = __builtin_amdgcn_mfma_f32_16x16x32_bf16(a3, b, acc[t][3], 0, 0, 0);
    }
}

// ---------------- fused per-level kernel, grid (5 strips, count nodes) ------
// waves 0..2: gate i/o/u preact; wave 3: forget-left; wave 4: forget-right
__global__ __launch_bounds__(320) void level_kernel(
    const unsigned short* __restrict__ AembT, const unsigned short* __restrict__ BW,
    const float* __restrict__ b_iou, const float* __restrict__ b_f,
    unsigned short* __restrict__ HbfT, float* __restrict__ C,
    int base, int is_leaf)
{
    __shared__ unsigned short sm[12 * TS];   // 2 bufs x (A0,A1,B0..B3) = 48 KB
    int p = base + blockIdx.y;
    int s = blockIdx.x;
    int tid = threadIdx.x;
    int w = tid >> 6, lane = tid & 63, ln = lane & 15, quad = lane >> 4;
    int l = 2 * p + 1, r = 2 * p + 2;
    int bsel = (w < 4) ? w : 3;
    const unsigned short* Bsrc = BW + (size_t)(bsel * 5 + s) * 17 * TS;
    const unsigned short* Ae = AembT + (size_t)p * 7 * TS;
    const unsigned short* Hl = HbfT + (size_t)l * 10 * TS;
    const unsigned short* Hr = HbfT + (size_t)r * 10 * TS;
    int ctot = is_leaf ? 7 : 17;

    f32x4 acc[4][4];
#pragma unroll
    for (int t = 0; t < 4; ++t)
#pragma unroll
        for (int q = 0; q < 4; ++q) acc[t][q] = (f32x4){0.f, 0.f, 0.f, 0.f};

    auto stage = [&](int c, int buf) {
        unsigned short* bb = sm + buf * 6 * TS;
        if (c < 7) {
            if (w < 4) stage_tile(Bsrc + (size_t)c * TS, bb + (2 + w) * TS, lane);
            else       stage_tile(Ae + (size_t)c * TS, bb, lane);
        } else {
            int hc = c - 7;
            if (w < 3)       stage_tile(Bsrc + (size_t)c * TS, bb + (2 + w) * TS, lane);
            else if (w == 3) { stage_tile(Bsrc + (size_t)c * TS, bb + 5 * TS, lane);
                               stage_tile(Hl + (size_t)hc * TS, bb, lane); }
            else             stage_tile(Hr + (size_t)hc * TS, bb + TS, lane);
        }
    };
    auto compute = [&](int c, int buf) {
        unsigned short* bb = sm + buf * 6 * TS;
        const unsigned short* Bt = bb + (2 + bsel) * TS;
        if (c < 7) {
            mfma_chunk(acc, bb, Bt, ln, quad);
        } else if (w < 3) {
            mfma_chunk(acc, bb, Bt, ln, quad);
            mfma_chunk(acc, bb + TS, Bt, ln, quad);
        } else if (w == 3) {
            mfma_chunk(acc, bb, Bt, ln, quad);
        } else {
            mfma_chunk(acc, bb + TS, Bt, ln, quad);
        }
    };

    stage(0, 0);
    for (int c = 0; c < ctot; ++c) {
        int cur = c & 1;
        __syncthreads();                       // drains stage(c); frees buf cur^1
        if (c + 1 < ctot) stage(c + 1, cur ^ 1);
        compute(c, cur);
    }

    // epilogue: exchange through LDS, fused gates + cell update
    float* tile = (float*)sm;                  // 5*64*16 f32 = 20 KB
    for (int t = 0; t < 4; ++t) {
        __syncthreads();
#pragma unroll
        for (int ms = 0; ms < 4; ++ms)
#pragma unroll
            for (int rr = 0; rr < 4; ++rr)
                tile[(w * 64 + ms * 16 + quad * 4 + rr) * 16 + ln] = acc[t][ms][rr];
        __syncthreads();
        for (int idx = tid; idx < 1024; idx += 320) {
            int m = idx >> 4, n = idx & 15;
            int jj = s * 64 + t * 16 + n;      // 0..319
            bool ok = jj < NH;
            float pi = tile[(0 * 64 + m) * 16 + n] + (ok ? b_iou[jj] : 0.f);
            float po = tile[(1 * 64 + m) * 16 + n] + (ok ? b_iou[NH + jj] : 0.f);
            float pu = tile[(2 * 64 + m) * 16 + n] + (ok ? b_iou[2 * NH + jj] : 0.f);
            float cc;
            if (is_leaf) {
                cc = sigmoidf_(pi) * tanhf(pu);
            } else {
                float bj = ok ? b_f[jj] : 0.f;
                float fl = sigmoidf_(tile[(3 * 64 + m) * 16 + n] + bj);
                float fr = sigmoidf_(tile[(4 * 64 + m) * 16 + n] + bj);
                float cl = ok ? C[((size_t)l * NB + m) * NH + jj] : 0.f;
                float cr = ok ? C[((size_t)r * NB + m) * NH + jj] : 0.f;
                cc = sigmoidf_(pi) * tanhf(pu) + fl * cl + fr * cr;
            }
            float hh = sigmoidf_(po) * tanhf(cc);
            if (ok) C[((size_t)p * NB + m) * NH + jj] = cc;
            HbfT[((size_t)p * 10 + (jj >> 5)) * TS + swz(m, jj & 31)]
                = ok ? f2bf(hh) : (unsigned short)0;
        }
    }
}

// ---------------- root -> logits -> log_softmax -----------------------------
__global__ __launch_bounds__(64) void out_kernel(
    const unsigned short* __restrict__ HbfT,
    const float* __restrict__ W_out, const float* __restrict__ b_out,
    float* __restrict__ out)
{
    int b = threadIdx.x;
    float l0 = 0.f, l1 = 0.f;
#pragma unroll 4
    for (int k = 0; k < NH; ++k) {
        float hk = bf2f(HbfT[(size_t)(k >> 5) * TS + swz(b, k & 31)]);
        l0 += hk * W_out[k * 2];
        l1 += hk * W_out[k * 2 + 1];
    }
    l0 += b_out[0];
    l1 += b_out[1];
    float m = fmaxf(l0, l1);
    float lse = m + logf(__expf(l0 - m) + __expf(l1 - m));
    out[b * 2 + 0] = l0 - lse;
    out[b * 2 + 1] = l1 - lse;
}

extern "C" void kernel_launch(void* const* d_in, const int* in_sizes, int n_in,
                              void* d_out, int out_size, void* d_ws, size_t ws_size,
                              hipStream_t stream)
{
    const int*   x     = (const int*)d_in[0];
    const float* embed = (const float*)d_in[3];
    const float* W_iou = (const float*)d_in[4];
    const float* U_iou = (const float*)d_in[5];
    const float* b_iou = (const float*)d_in[6];
    const float* W_f   = (const float*)d_in[7];
    const float* U_f   = (const float*)d_in[8];
    const float* b_f   = (const float*)d_in[9];
    const float* W_out = (const float*)d_in[10];
    const float* b_out = (const float*)d_in[11];

    char* ws = (char*)d_ws;
    unsigned short* HbfT  = (unsigned short*)(ws + 0);
    float*          C     = (float*)(ws + 10444800);
    unsigned short* AembT = (unsigned short*)(ws + 30028800);
    unsigned short* BW    = (unsigned short*)(ws + 37340160);

    prep_kernel<<<4096, 256, 0, stream>>>(U_iou, U_f, W_iou, W_f, embed, x, BW, AembT);

    for (int d = 7; d >= 0; --d) {
        int base = (1 << d) - 1;
        int count = 1 << d;
        dim3 grid(5, count);
        level_kernel<<<grid, 320, 0, stream>>>(AembT, BW, b_iou, b_f, HbfT, C,
                                               base, d == 7 ? 1 : 0);
    }
    out_kernel<<<1, 64, 0, stream>>>(HbfT, W_out, b_out, (float*)d_out);
}